// Round 13
// baseline (581.617 us; speedup 1.0000x reference)
//
#include <hip/hip_runtime.h>
#include <hip/hip_fp16.h>
#include <math.h>

#define N_NODES 50000
#define N_EDGES 1600000
#define SLOTS 96            // padded CSR row capacity; deg~Binom(1.6M,1/50k): P(>=96) ~ 1e-18
#define NODES_PER_GRP 6250  // 50000 / 8 XCD ranges
#define E4T (N_EDGES / 4)   // 400000 int4 positions
#define CH4 2048            // int4 per dynamic chunk (8 per thread)

typedef int v4i __attribute__((ext_vector_type(4)));

// ---------------------------------------------------------------------------
// Padded-CSR build, physical-XCD-owned scatter.
// Round-9 lesson: WRITE_SIZE (61MB vs ~10MB ideal) was invariant under
// nt-loads, occupancy, and time-phasing -> amplification is cross-XCD
// dirty-line sharing, because blockIdx&7 does NOT track the real XCD.
// Fix: read HW_REG_XCC_ID; blocks on XCD g exclusively scatter dst range g,
// so each ssrc/cursor line is dirtied by exactly one L2. Each XCD streams
// the full edge list via its own dynamic chunk queue; idle blocks drain
// other queues as a correctness fallback (atomics stay correct regardless
// of which CU executes them - only locality/speed would degrade).
// ---------------------------------------------------------------------------

__global__ void zero_kernel(int* p, int n) {
    int i = blockIdx.x * blockDim.x + threadIdx.x;
    if (i < n) p[i] = 0;
}

__device__ __forceinline__ int get_xcd() {
    int x;
    asm volatile("s_getreg_b32 %0, hwreg(HW_REG_XCC_ID)" : "=s"(x));
    return x & 7;
}

__global__ __launch_bounds__(256) void fill_xcd_kernel(
    const int* __restrict__ src, const int* __restrict__ dst,
    int* __restrict__ cursor, int* __restrict__ ssrc,
    int* __restrict__ work) {   // work[8]: per-XCD chunk queues (pre-zeroed)
    const int xcd = get_xcd();
    const v4i* d4 = (const v4i*)dst;
    const v4i* s4 = (const v4i*)src;
    __shared__ int sbase;

    for (int qi = 0; qi < 8; ++qi) {
        const int q = (xcd + qi) & 7;     // own queue first, then fallback
        const int lo = q * NODES_PER_GRP;
        const int hi = lo + NODES_PER_GRP;
        for (;;) {
            if (threadIdx.x == 0) sbase = atomicAdd(&work[q], CH4);
            __syncthreads();
            const int base = sbase;
            __syncthreads();
            if (base >= E4T) break;       // uniform: all lanes read same sbase
            const int lim = (base + CH4 < E4T) ? base + CH4 : E4T;
#pragma unroll
            for (int k = 0; k < CH4 / 256; ++k) {
                const int i = base + k * 256 + (int)threadIdx.x;
                if (i < lim) {
                    v4i d = __builtin_nontemporal_load(d4 + i);
                    v4i s = __builtin_nontemporal_load(s4 + i);
                    if (d.x >= lo && d.x < hi) {
                        int p = atomicAdd(&cursor[d.x], 1);
                        if (p < SLOTS) ssrc[d.x * SLOTS + p] = s.x;
                    }
                    if (d.y >= lo && d.y < hi) {
                        int p = atomicAdd(&cursor[d.y], 1);
                        if (p < SLOTS) ssrc[d.y * SLOTS + p] = s.y;
                    }
                    if (d.z >= lo && d.z < hi) {
                        int p = atomicAdd(&cursor[d.z], 1);
                        if (p < SLOTS) ssrc[d.z * SLOTS + p] = s.z;
                    }
                    if (d.w >= lo && d.w < hi) {
                        int p = atomicAdd(&cursor[d.w], 1);
                        if (p < SLOTS) ssrc[d.w * SLOTS + p] = s.w;
                    }
                }
            }
        }
    }
}

// ---------------------------------------------------------------------------
// GEMM + fused el/er epilogue. feat is stored fp16 (only the aggregate's
// gathered multiplicand is rounded; el/er come from the fp32 accumulators).
// ---------------------------------------------------------------------------

template <int K>
__global__ __launch_bounds__(256) void gemm_elr_kernel(
    const float* __restrict__ x,    // [N,K]
    const float* __restrict__ W,    // [K,128]
    const float* __restrict__ al,   // [128]
    const float* __restrict__ ar,   // [128]
    __half* __restrict__ feat,      // [N,128] fp16
    float* __restrict__ el,         // [N,2]
    float* __restrict__ er,         // [N,2]
    int N) {
    constexpr int LDX = K + 4;
    __shared__ float xs[32 * LDX];
    const int tid = threadIdx.x;
    const int node0 = blockIdx.x * 32;

    for (int i = tid; i < 32 * K / 4; i += 256) {
        int r = i / (K / 4), c4 = i % (K / 4);
        float4 v = make_float4(0.f, 0.f, 0.f, 0.f);
        if (node0 + r < N) v = *(const float4*)&x[(size_t)(node0 + r) * K + c4 * 4];
        *(float4*)&xs[r * LDX + c4 * 4] = v;
    }
    __syncthreads();

    const int tx = tid & 31;
    const int ty = tid >> 5;
    const int col = tx * 4;

    float acc[4][4];
#pragma unroll
    for (int r = 0; r < 4; ++r)
#pragma unroll
        for (int c = 0; c < 4; ++c) acc[r][c] = 0.f;

    for (int kb = 0; kb < K / 4; ++kb) {
        float4 w0 = *(const float4*)&W[(kb * 4 + 0) * 128 + col];
        float4 w1 = *(const float4*)&W[(kb * 4 + 1) * 128 + col];
        float4 w2 = *(const float4*)&W[(kb * 4 + 2) * 128 + col];
        float4 w3 = *(const float4*)&W[(kb * 4 + 3) * 128 + col];
        float4 xv[4];
#pragma unroll
        for (int r = 0; r < 4; ++r)
            xv[r] = *(const float4*)&xs[(ty * 4 + r) * LDX + kb * 4];
#pragma unroll
        for (int r = 0; r < 4; ++r) {
            acc[r][0] += xv[r].x * w0.x + xv[r].y * w1.x + xv[r].z * w2.x + xv[r].w * w3.x;
            acc[r][1] += xv[r].x * w0.y + xv[r].y * w1.y + xv[r].z * w2.y + xv[r].w * w3.y;
            acc[r][2] += xv[r].x * w0.z + xv[r].y * w1.z + xv[r].z * w2.z + xv[r].w * w3.z;
            acc[r][3] += xv[r].x * w0.w + xv[r].y * w1.w + xv[r].z * w2.w + xv[r].w * w3.w;
        }
    }

    float4 alv = *(const float4*)&al[col];
    float4 arv = *(const float4*)&ar[col];
    float elp[4], erp[4];
#pragma unroll
    for (int r = 0; r < 4; ++r) {
        int n = node0 + ty * 4 + r;
        float4 f = make_float4(acc[r][0], acc[r][1], acc[r][2], acc[r][3]);
        if (n < N) {
            __half2 p0 = __floats2half2_rn(f.x, f.y);
            __half2 p1 = __floats2half2_rn(f.z, f.w);
            union { __half2 h2[2]; uint2 u; } pk;
            pk.h2[0] = p0; pk.h2[1] = p1;
            *(uint2*)&feat[(size_t)n * 128 + col] = pk.u;
        }
        elp[r] = f.x * alv.x + f.y * alv.y + f.z * alv.z + f.w * alv.w;
        erp[r] = f.x * arv.x + f.y * arv.y + f.z * arv.z + f.w * arv.w;
    }
#pragma unroll
    for (int m = 1; m <= 8; m <<= 1) {
#pragma unroll
        for (int r = 0; r < 4; ++r) {
            elp[r] += __shfl_xor(elp[r], m, 64);
            erp[r] += __shfl_xor(erp[r], m, 64);
        }
    }
    int h = tx >> 4;
    if ((tx & 15) == 0) {
#pragma unroll
        for (int r = 0; r < 4; ++r) {
            int n = node0 + ty * 4 + r;
            if (n < N) {
                el[n * 2 + h] = elp[r];
                er[n * 2 + h] = erp[r];
            }
        }
    }
}

// ---------------------------------------------------------------------------
// Aggregation over fp16 feat rows (256 B each). One wave per node.
// Quarter-wave split: q = lane>>4 picks edge base+q (4 edges/iter), lane
// ql = lane&15 owns halves [ql*8, ql*8+8) of the 128-half row -> one
// dwordx4 load per lane = 4 full rows (1 KB) per instruction per wave.
// ---------------------------------------------------------------------------

__global__ __launch_bounds__(256) void aggregate_kernel(
    const __half* __restrict__ feat,  // [N,128] fp16
    const float* __restrict__ el,     // [N,2]
    const float* __restrict__ er,     // [N,2]
    const int* __restrict__ deg,      // [N]
    const int* __restrict__ ssrc,     // [N*SLOTS]
    const float* __restrict__ bias,   // [128]
    float* __restrict__ hout,         // [N,64]
    int N) {
    const int wave = threadIdx.x >> 6;
    const int lane = threadIdx.x & 63;
    const int n = blockIdx.x * 4 + wave;
    if (n >= N) return;

    const int q = lane >> 4;    // edge slot within a group of 4
    const int ql = lane & 15;   // column group: halves ql*8 .. ql*8+7
    const int h = ql >> 3;      // head of my columns
    const float er_h = er[n * 2 + h];
    const int start = n * SLOTS;
    int d = deg[n];
    if (d > SLOTS) d = SLOTS;

    float acc[8];
#pragma unroll
    for (int j = 0; j < 8; ++j) acc[j] = 0.f;
    float ssum = 0.f;

#pragma unroll 2
    for (int base = 0; base < d; base += 4) {
        int idx = base + q;
        bool valid = idx < d;
        int s = ssrc[start + (valid ? idx : 0)];
        float e = el[s * 2 + h] + er_h;
        e = e > 0.f ? e : 0.2f * e;
        float x = valid ? __expf(e) : 0.f;
        float4 raw = *(const float4*)(feat + (size_t)s * 128 + ql * 8);
        const __half2* hp = (const __half2*)&raw;
        float2 f0 = __half22float2(hp[0]);
        float2 f1 = __half22float2(hp[1]);
        float2 f2 = __half22float2(hp[2]);
        float2 f3 = __half22float2(hp[3]);
        ssum += x;
        acc[0] += x * f0.x; acc[1] += x * f0.y;
        acc[2] += x * f1.x; acc[3] += x * f1.y;
        acc[4] += x * f2.x; acc[5] += x * f2.y;
        acc[6] += x * f3.x; acc[7] += x * f3.y;
    }

    // merge the 4 quarter-waves (lanes with equal ql)
#pragma unroll
    for (int m = 16; m <= 32; m <<= 1) {
#pragma unroll
        for (int j = 0; j < 8; ++j) acc[j] += __shfl_xor(acc[j], m, 64);
        ssum += __shfl_xor(ssum, m, 64);
    }

    float inv = (d > 0) ? 1.0f / ssum : 0.0f;
    float4 b0 = *(const float4*)&bias[ql * 8];
    float4 b1 = *(const float4*)&bias[ql * 8 + 4];
    float v[8];
    v[0] = acc[0] * inv + b0.x; v[1] = acc[1] * inv + b0.y;
    v[2] = acc[2] * inv + b0.z; v[3] = acc[3] * inv + b0.w;
    v[4] = acc[4] * inv + b1.x; v[5] = acc[5] * inv + b1.y;
    v[6] = acc[6] * inv + b1.z; v[7] = acc[7] * inv + b1.w;

    // mean over heads: lane ql^8 holds the other head's same within-head cols
    float o[8];
#pragma unroll
    for (int j = 0; j < 8; ++j) {
        float p = __shfl_xor(v[j], 8, 64);
        float t = 0.5f * (v[j] + p);
        o[j] = t > 0.f ? t : expm1f(t);
    }
    if (lane < 8) {  // q==0, ql<8: write cols ql*8 .. ql*8+7
        float4 w0 = make_float4(o[0], o[1], o[2], o[3]);
        float4 w1 = make_float4(o[4], o[5], o[6], o[7]);
        *(float4*)&hout[(size_t)n * 64 + ql * 8] = w0;
        *(float4*)&hout[(size_t)n * 64 + ql * 8 + 4] = w1;
    }
}

// ---------------------------------------------------------------------------

extern "C" void kernel_launch(void* const* d_in, const int* in_sizes, int n_in,
                              void* d_out, int out_size, void* d_ws, size_t ws_size,
                              hipStream_t stream) {
    const float* features = (const float*)d_in[0];
    const float* W1 = (const float*)d_in[1];
    const float* al1 = (const float*)d_in[2];
    const float* ar1 = (const float*)d_in[3];
    const float* b1 = (const float*)d_in[4];
    const float* W2 = (const float*)d_in[5];
    const float* al2 = (const float*)d_in[6];
    const float* ar2 = (const float*)d_in[7];
    const float* b2 = (const float*)d_in[8];
    const int* src = (const int*)d_in[9];
    const int* dst = (const int*)d_in[10];
    float* out = (float*)d_out;

    const int N = N_NODES;

    char* ws = (char*)d_ws;
    size_t off = 0;
    auto alloc = [&](size_t bytes) {
        void* p = ws + off;
        off = (off + bytes + 255) & ~255ULL;
        return p;
    };
    int* cursor   = (int*)alloc((size_t)(N + 8) * 4);     // + work[8] queues
    int* work     = cursor + N;
    int* ssrc     = (int*)alloc((size_t)N * SLOTS * 4);   // 19.2 MB padded CSR
    __half* feath = (__half*)alloc((size_t)N * 128 * 2);  // 12.8 MB fp16 feat
    float* el     = (float*)alloc((size_t)N * 2 * 4);
    float* er     = (float*)alloc((size_t)N * 2 * 4);
    float* h1     = (float*)alloc((size_t)N * 64 * 4);

    // padded-CSR build (shared by both layers): physical-XCD-owned scatter
    zero_kernel<<<(N + 8 + 255) / 256, 256, 0, stream>>>(cursor, N + 8);
    fill_xcd_kernel<<<2048, 256, 0, stream>>>(src, dst, cursor, ssrc, work);

    // layer 1
    gemm_elr_kernel<128><<<(N + 31) / 32, 256, 0, stream>>>(features, W1, al1, ar1,
                                                            feath, el, er, N);
    aggregate_kernel<<<(N + 3) / 4, 256, 0, stream>>>(feath, el, er, cursor, ssrc,
                                                      b1, h1, N);
    // layer 2
    gemm_elr_kernel<64><<<(N + 31) / 32, 256, 0, stream>>>(h1, W2, al2, ar2,
                                                           feath, el, er, N);
    aggregate_kernel<<<(N + 3) / 4, 256, 0, stream>>>(feath, el, er, cursor, ssrc,
                                                      b2, out, N);
}

// Round 14
// 411.852 us; speedup vs baseline: 1.4122x; 1.4122x over previous
//
#include <hip/hip_runtime.h>
#include <hip/hip_fp16.h>
#include <math.h>

#define N_NODES 50000
#define N_EDGES 1600000
#define SLOTS 96            // padded CSR row capacity; P(deg>=96) ~ 1e-18
#define NODES_PER_GRP 6250  // 50000 / 8 groups

typedef int v4i __attribute__((ext_vector_type(4)));

// ---------------------------------------------------------------------------
// Padded-CSR build. 8 dst-groups; each group streams the whole edge list
// (int4, nt). Measured floor ~79us: WRITE_SIZE ~61MB is the 1.6M device-scope
// atomicAdds themselves (~32B fabric RMW each at the cross-XCD coherence
// point) + ~10MB ssrc flushes — invariant across 4 structurally different
// fills, so locality tricks can't reduce it. Only micro-opt left: issue all
// 4 atomics before the dependent stores so the RMWs overlap.
// ---------------------------------------------------------------------------

__global__ void zero_kernel(int* p, int n) {
    int i = blockIdx.x * blockDim.x + threadIdx.x;
    if (i < n) p[i] = 0;
}

__global__ __launch_bounds__(256) void fill_part_kernel(
    const int* __restrict__ src, const int* __restrict__ dst,
    int* __restrict__ cursor, int* __restrict__ ssrc, int E) {
    const int g = blockIdx.x & 7;
    const int bg = blockIdx.x >> 3;
    const int nbg = gridDim.x >> 3;
    const int lo = g * NODES_PER_GRP;
    const int hi = lo + NODES_PER_GRP;
    const v4i* d4 = (const v4i*)dst;
    const v4i* s4 = (const v4i*)src;
    const int E4 = E >> 2;

    for (int i = bg * 256 + threadIdx.x; i < E4; i += nbg * 256) {
        v4i d = __builtin_nontemporal_load(d4 + i);
        v4i s = __builtin_nontemporal_load(s4 + i);
        const bool c0 = d.x >= lo && d.x < hi;
        const bool c1 = d.y >= lo && d.y < hi;
        const bool c2 = d.z >= lo && d.z < hi;
        const bool c3 = d.w >= lo && d.w < hi;
        int p0, p1, p2, p3;
        if (c0) p0 = atomicAdd(&cursor[d.x], 1);
        if (c1) p1 = atomicAdd(&cursor[d.y], 1);
        if (c2) p2 = atomicAdd(&cursor[d.z], 1);
        if (c3) p3 = atomicAdd(&cursor[d.w], 1);
        if (c0 && p0 < SLOTS) ssrc[d.x * SLOTS + p0] = s.x;
        if (c1 && p1 < SLOTS) ssrc[d.y * SLOTS + p1] = s.y;
        if (c2 && p2 < SLOTS) ssrc[d.z * SLOTS + p2] = s.z;
        if (c3 && p3 < SLOTS) ssrc[d.w * SLOTS + p3] = s.w;
    }
}

// ---------------------------------------------------------------------------
// GEMM + fused el/er epilogue. feat is stored fp16 (only the aggregate's
// gathered multiplicand is rounded; el/er come from the fp32 accumulators).
// ---------------------------------------------------------------------------

template <int K>
__global__ __launch_bounds__(256) void gemm_elr_kernel(
    const float* __restrict__ x,    // [N,K]
    const float* __restrict__ W,    // [K,128]
    const float* __restrict__ al,   // [128]
    const float* __restrict__ ar,   // [128]
    __half* __restrict__ feat,      // [N,128] fp16
    float* __restrict__ el,         // [N,2]
    float* __restrict__ er,         // [N,2]
    int N) {
    constexpr int LDX = K + 4;
    __shared__ float xs[32 * LDX];
    const int tid = threadIdx.x;
    const int node0 = blockIdx.x * 32;

    for (int i = tid; i < 32 * K / 4; i += 256) {
        int r = i / (K / 4), c4 = i % (K / 4);
        float4 v = make_float4(0.f, 0.f, 0.f, 0.f);
        if (node0 + r < N) v = *(const float4*)&x[(size_t)(node0 + r) * K + c4 * 4];
        *(float4*)&xs[r * LDX + c4 * 4] = v;
    }
    __syncthreads();

    const int tx = tid & 31;
    const int ty = tid >> 5;
    const int col = tx * 4;

    float acc[4][4];
#pragma unroll
    for (int r = 0; r < 4; ++r)
#pragma unroll
        for (int c = 0; c < 4; ++c) acc[r][c] = 0.f;

    for (int kb = 0; kb < K / 4; ++kb) {
        float4 w0 = *(const float4*)&W[(kb * 4 + 0) * 128 + col];
        float4 w1 = *(const float4*)&W[(kb * 4 + 1) * 128 + col];
        float4 w2 = *(const float4*)&W[(kb * 4 + 2) * 128 + col];
        float4 w3 = *(const float4*)&W[(kb * 4 + 3) * 128 + col];
        float4 xv[4];
#pragma unroll
        for (int r = 0; r < 4; ++r)
            xv[r] = *(const float4*)&xs[(ty * 4 + r) * LDX + kb * 4];
#pragma unroll
        for (int r = 0; r < 4; ++r) {
            acc[r][0] += xv[r].x * w0.x + xv[r].y * w1.x + xv[r].z * w2.x + xv[r].w * w3.x;
            acc[r][1] += xv[r].x * w0.y + xv[r].y * w1.y + xv[r].z * w2.y + xv[r].w * w3.y;
            acc[r][2] += xv[r].x * w0.z + xv[r].y * w1.z + xv[r].z * w2.z + xv[r].w * w3.z;
            acc[r][3] += xv[r].x * w0.w + xv[r].y * w1.w + xv[r].z * w2.w + xv[r].w * w3.w;
        }
    }

    float4 alv = *(const float4*)&al[col];
    float4 arv = *(const float4*)&ar[col];
    float elp[4], erp[4];
#pragma unroll
    for (int r = 0; r < 4; ++r) {
        int n = node0 + ty * 4 + r;
        float4 f = make_float4(acc[r][0], acc[r][1], acc[r][2], acc[r][3]);
        if (n < N) {
            __half2 p0 = __floats2half2_rn(f.x, f.y);
            __half2 p1 = __floats2half2_rn(f.z, f.w);
            union { __half2 h2[2]; uint2 u; } pk;
            pk.h2[0] = p0; pk.h2[1] = p1;
            *(uint2*)&feat[(size_t)n * 128 + col] = pk.u;
        }
        elp[r] = f.x * alv.x + f.y * alv.y + f.z * alv.z + f.w * alv.w;
        erp[r] = f.x * arv.x + f.y * arv.y + f.z * arv.z + f.w * arv.w;
    }
#pragma unroll
    for (int m = 1; m <= 8; m <<= 1) {
#pragma unroll
        for (int r = 0; r < 4; ++r) {
            elp[r] += __shfl_xor(elp[r], m, 64);
            erp[r] += __shfl_xor(erp[r], m, 64);
        }
    }
    int h = tx >> 4;
    if ((tx & 15) == 0) {
#pragma unroll
        for (int r = 0; r < 4; ++r) {
            int n = node0 + ty * 4 + r;
            if (n < N) {
                el[n * 2 + h] = elp[r];
                er[n * 2 + h] = erp[r];
            }
        }
    }
}

// ---------------------------------------------------------------------------
// Aggregation over fp16 feat rows (256 B each). One wave per node.
// 8-way edge split for MLP: q = lane>>3 picks edge base+q (8 edges/iter);
// lane ql = lane&7 owns halves [ql*16, ql*16+16) of the 128-half row ->
// two dwordx4 loads per lane = 8 full rows (2 KB) in flight per wave-iter
// (prev layout kept only 4; VGPR was 20 -> latency-bound).
// Merge q-groups via shfl_xor 8/16/32; head-mean via shfl_xor 4.
// ---------------------------------------------------------------------------

__global__ __launch_bounds__(256) void aggregate_kernel(
    const __half* __restrict__ feat,  // [N,128] fp16
    const float* __restrict__ el,     // [N,2]
    const float* __restrict__ er,     // [N,2]
    const int* __restrict__ deg,      // [N]
    const int* __restrict__ ssrc,     // [N*SLOTS]
    const float* __restrict__ bias,   // [128]
    float* __restrict__ hout,         // [N,64]
    int N) {
    const int wave = threadIdx.x >> 6;
    const int lane = threadIdx.x & 63;
    const int n = blockIdx.x * 4 + wave;
    if (n >= N) return;

    const int q = lane >> 3;    // edge slot within a group of 8
    const int ql = lane & 7;    // column group: halves ql*16 .. ql*16+15
    const int h = ql >> 2;      // head of my columns
    const float er_h = er[n * 2 + h];
    const int start = n * SLOTS;
    int d = deg[n];
    if (d > SLOTS) d = SLOTS;

    float acc[16];
#pragma unroll
    for (int j = 0; j < 16; ++j) acc[j] = 0.f;
    float ssum = 0.f;

    for (int base = 0; base < d; base += 8) {
        int idx = base + q;
        bool valid = idx < d;
        int s = ssrc[start + (valid ? idx : 0)];
        float e = el[s * 2 + h] + er_h;
        e = e > 0.f ? e : 0.2f * e;
        float x = valid ? __expf(e) : 0.f;
        const float4* fp = (const float4*)(feat + (size_t)s * 128 + ql * 16);
        float4 ra = fp[0];
        float4 rb = fp[1];
        const __half2* ha = (const __half2*)&ra;
        const __half2* hb = (const __half2*)&rb;
        ssum += x;
#pragma unroll
        for (int j = 0; j < 4; ++j) {
            float2 fa = __half22float2(ha[j]);
            float2 fb = __half22float2(hb[j]);
            acc[j * 2 + 0] += x * fa.x;
            acc[j * 2 + 1] += x * fa.y;
            acc[8 + j * 2 + 0] += x * fb.x;
            acc[8 + j * 2 + 1] += x * fb.y;
        }
    }

    // merge the 8 q-groups (lanes with equal ql)
#pragma unroll
    for (int m = 8; m <= 32; m <<= 1) {
#pragma unroll
        for (int j = 0; j < 16; ++j) acc[j] += __shfl_xor(acc[j], m, 64);
        ssum += __shfl_xor(ssum, m, 64);
    }

    float inv = (d > 0) ? 1.0f / ssum : 0.0f;
    float v[16];
#pragma unroll
    for (int j = 0; j < 4; ++j) {
        float4 b = *(const float4*)&bias[ql * 16 + j * 4];
        v[j * 4 + 0] = acc[j * 4 + 0] * inv + b.x;
        v[j * 4 + 1] = acc[j * 4 + 1] * inv + b.y;
        v[j * 4 + 2] = acc[j * 4 + 2] * inv + b.z;
        v[j * 4 + 3] = acc[j * 4 + 3] * inv + b.w;
    }

    // mean over heads: lane ql^4 holds the other head's same within-head cols
    float o[16];
#pragma unroll
    for (int j = 0; j < 16; ++j) {
        float p = __shfl_xor(v[j], 4, 64);
        float t = 0.5f * (v[j] + p);
        o[j] = t > 0.f ? t : expm1f(t);
    }
    if (lane < 4) {  // q==0, ql<4: write within-head cols [ql*16, ql*16+16)
#pragma unroll
        for (int j = 0; j < 4; ++j) {
            float4 w = make_float4(o[j * 4 + 0], o[j * 4 + 1], o[j * 4 + 2], o[j * 4 + 3]);
            *(float4*)&hout[(size_t)n * 64 + ql * 16 + j * 4] = w;
        }
    }
}

// ---------------------------------------------------------------------------

extern "C" void kernel_launch(void* const* d_in, const int* in_sizes, int n_in,
                              void* d_out, int out_size, void* d_ws, size_t ws_size,
                              hipStream_t stream) {
    const float* features = (const float*)d_in[0];
    const float* W1 = (const float*)d_in[1];
    const float* al1 = (const float*)d_in[2];
    const float* ar1 = (const float*)d_in[3];
    const float* b1 = (const float*)d_in[4];
    const float* W2 = (const float*)d_in[5];
    const float* al2 = (const float*)d_in[6];
    const float* ar2 = (const float*)d_in[7];
    const float* b2 = (const float*)d_in[8];
    const int* src = (const int*)d_in[9];
    const int* dst = (const int*)d_in[10];
    float* out = (float*)d_out;

    const int N = N_NODES;
    const int E = N_EDGES;

    char* ws = (char*)d_ws;
    size_t off = 0;
    auto alloc = [&](size_t bytes) {
        void* p = ws + off;
        off = (off + bytes + 255) & ~255ULL;
        return p;
    };
    int* cursor   = (int*)alloc((size_t)N * 4);
    int* ssrc     = (int*)alloc((size_t)N * SLOTS * 4);   // 19.2 MB padded CSR
    __half* feath = (__half*)alloc((size_t)N * 128 * 2);  // 12.8 MB fp16 feat
    float* el     = (float*)alloc((size_t)N * 2 * 4);
    float* er     = (float*)alloc((size_t)N * 2 * 4);
    float* h1     = (float*)alloc((size_t)N * 64 * 4);

    // padded-CSR build (shared by both layers): measured-best 832-block config
    zero_kernel<<<(N + 255) / 256, 256, 0, stream>>>(cursor, N);
    fill_part_kernel<<<8 * 104, 256, 0, stream>>>(src, dst, cursor, ssrc, E);

    // layer 1
    gemm_elr_kernel<128><<<(N + 31) / 32, 256, 0, stream>>>(features, W1, al1, ar1,
                                                            feath, el, er, N);
    aggregate_kernel<<<(N + 3) / 4, 256, 0, stream>>>(feath, el, er, cursor, ssrc,
                                                      b1, h1, N);
    // layer 2
    gemm_elr_kernel<64><<<(N + 31) / 32, 256, 0, stream>>>(h1, W2, al2, ar2,
                                                           feath, el, er, N);
    aggregate_kernel<<<(N + 3) / 4, 256, 0, stream>>>(feath, el, er, cursor, ssrc,
                                                      b2, out, N);
}

// Round 15
// 390.559 us; speedup vs baseline: 1.4892x; 1.0545x over previous
//
#include <hip/hip_runtime.h>
#include <hip/hip_fp16.h>
#include <math.h>

#define N_NODES 50000
#define N_EDGES 1600000
#define SLOTS 96            // padded CSR row capacity; P(deg>=96) ~ 1e-18
#define NODES_PER_GRP 6250  // 50000 / 8 groups
#define FILL_BLOCKS 832     // 8 groups x 104 (measured-best round-6 config)
#define GEMM1_BLOCKS ((N_NODES + 31) / 32)

typedef int v4i __attribute__((ext_vector_type(4)));

// ---------------------------------------------------------------------------
// Fused CSR-fill + layer-1 GEMM. The two are data-independent; fill is
// latency-bound (27% occupancy, 3% VALU, 16% HBM), so the GEMM blocks hide
// inside its stalls. Blocks [0,832) run fill; [832, 832+1563) run GEMM K=128.
// Fill: WRITE_SIZE ~61MB is intrinsic (1.6M device-scope atomic RMWs ~32B
// each at the cross-XCD coherence point) — proven invariant across 5 fill
// structures; round-6 interleaved form is the measured-best (78.6us).
// ---------------------------------------------------------------------------

__global__ __launch_bounds__(256) void fused_fill_gemm1(
    const int* __restrict__ src, const int* __restrict__ dst,
    int* __restrict__ cursor, int* __restrict__ ssrc,
    const float* __restrict__ x,    // [N,128] features
    const float* __restrict__ W,    // [128,128]
    const float* __restrict__ al,   // [128]
    const float* __restrict__ ar,   // [128]
    __half* __restrict__ feat,      // [N,128] fp16
    float* __restrict__ el,         // [N,2]
    float* __restrict__ er) {       // [N,2]
    constexpr int K = 128;
    constexpr int LDX = K + 4;
    __shared__ float xs[32 * LDX];

    if (blockIdx.x < FILL_BLOCKS) {
        // ---------------- fill body (round-6 exact) ----------------
        const int g = blockIdx.x & 7;
        const int bg = blockIdx.x >> 3;
        const int nbg = FILL_BLOCKS >> 3;
        const int lo = g * NODES_PER_GRP;
        const int hi = lo + NODES_PER_GRP;
        const v4i* d4 = (const v4i*)dst;
        const v4i* s4 = (const v4i*)src;
        const int E4 = N_EDGES >> 2;

        for (int i = bg * 256 + threadIdx.x; i < E4; i += nbg * 256) {
            v4i d = __builtin_nontemporal_load(d4 + i);
            v4i s = __builtin_nontemporal_load(s4 + i);
            if (d.x >= lo && d.x < hi) {
                int p = atomicAdd(&cursor[d.x], 1);
                if (p < SLOTS) ssrc[d.x * SLOTS + p] = s.x;
            }
            if (d.y >= lo && d.y < hi) {
                int p = atomicAdd(&cursor[d.y], 1);
                if (p < SLOTS) ssrc[d.y * SLOTS + p] = s.y;
            }
            if (d.z >= lo && d.z < hi) {
                int p = atomicAdd(&cursor[d.z], 1);
                if (p < SLOTS) ssrc[d.z * SLOTS + p] = s.z;
            }
            if (d.w >= lo && d.w < hi) {
                int p = atomicAdd(&cursor[d.w], 1);
                if (p < SLOTS) ssrc[d.w * SLOTS + p] = s.w;
            }
        }
        return;
    }

    // ---------------- GEMM K=128 body ----------------
    const int tid = threadIdx.x;
    const int node0 = (blockIdx.x - FILL_BLOCKS) * 32;
    const int N = N_NODES;

    for (int i = tid; i < 32 * K / 4; i += 256) {
        int r = i / (K / 4), c4 = i % (K / 4);
        float4 v = make_float4(0.f, 0.f, 0.f, 0.f);
        if (node0 + r < N) v = *(const float4*)&x[(size_t)(node0 + r) * K + c4 * 4];
        *(float4*)&xs[r * LDX + c4 * 4] = v;
    }
    __syncthreads();

    const int tx = tid & 31;
    const int ty = tid >> 5;
    const int col = tx * 4;

    float acc[4][4];
#pragma unroll
    for (int r = 0; r < 4; ++r)
#pragma unroll
        for (int c = 0; c < 4; ++c) acc[r][c] = 0.f;

    for (int kb = 0; kb < K / 4; ++kb) {
        float4 w0 = *(const float4*)&W[(kb * 4 + 0) * 128 + col];
        float4 w1 = *(const float4*)&W[(kb * 4 + 1) * 128 + col];
        float4 w2 = *(const float4*)&W[(kb * 4 + 2) * 128 + col];
        float4 w3 = *(const float4*)&W[(kb * 4 + 3) * 128 + col];
        float4 xv[4];
#pragma unroll
        for (int r = 0; r < 4; ++r)
            xv[r] = *(const float4*)&xs[(ty * 4 + r) * LDX + kb * 4];
#pragma unroll
        for (int r = 0; r < 4; ++r) {
            acc[r][0] += xv[r].x * w0.x + xv[r].y * w1.x + xv[r].z * w2.x + xv[r].w * w3.x;
            acc[r][1] += xv[r].x * w0.y + xv[r].y * w1.y + xv[r].z * w2.y + xv[r].w * w3.y;
            acc[r][2] += xv[r].x * w0.z + xv[r].y * w1.z + xv[r].z * w2.z + xv[r].w * w3.z;
            acc[r][3] += xv[r].x * w0.w + xv[r].y * w1.w + xv[r].z * w2.w + xv[r].w * w3.w;
        }
    }

    float4 alv = *(const float4*)&al[col];
    float4 arv = *(const float4*)&ar[col];
    float elp[4], erp[4];
#pragma unroll
    for (int r = 0; r < 4; ++r) {
        int n = node0 + ty * 4 + r;
        float4 f = make_float4(acc[r][0], acc[r][1], acc[r][2], acc[r][3]);
        if (n < N) {
            __half2 p0 = __floats2half2_rn(f.x, f.y);
            __half2 p1 = __floats2half2_rn(f.z, f.w);
            union { __half2 h2[2]; uint2 u; } pk;
            pk.h2[0] = p0; pk.h2[1] = p1;
            *(uint2*)&feat[(size_t)n * 128 + col] = pk.u;
        }
        elp[r] = f.x * alv.x + f.y * alv.y + f.z * alv.z + f.w * alv.w;
        erp[r] = f.x * arv.x + f.y * arv.y + f.z * arv.z + f.w * arv.w;
    }
#pragma unroll
    for (int m = 1; m <= 8; m <<= 1) {
#pragma unroll
        for (int r = 0; r < 4; ++r) {
            elp[r] += __shfl_xor(elp[r], m, 64);
            erp[r] += __shfl_xor(erp[r], m, 64);
        }
    }
    int h = tx >> 4;
    if ((tx & 15) == 0) {
#pragma unroll
        for (int r = 0; r < 4; ++r) {
            int n = node0 + ty * 4 + r;
            if (n < N) {
                el[n * 2 + h] = elp[r];
                er[n * 2 + h] = erp[r];
            }
        }
    }
}

// ---------------------------------------------------------------------------
// Standalone GEMM (layer 2, K=64) + fused el/er epilogue.
// ---------------------------------------------------------------------------

template <int K>
__global__ __launch_bounds__(256) void gemm_elr_kernel(
    const float* __restrict__ x, const float* __restrict__ W,
    const float* __restrict__ al, const float* __restrict__ ar,
    __half* __restrict__ feat, float* __restrict__ el, float* __restrict__ er,
    int N) {
    constexpr int LDX = K + 4;
    __shared__ float xs[32 * LDX];
    const int tid = threadIdx.x;
    const int node0 = blockIdx.x * 32;

    for (int i = tid; i < 32 * K / 4; i += 256) {
        int r = i / (K / 4), c4 = i % (K / 4);
        float4 v = make_float4(0.f, 0.f, 0.f, 0.f);
        if (node0 + r < N) v = *(const float4*)&x[(size_t)(node0 + r) * K + c4 * 4];
        *(float4*)&xs[r * LDX + c4 * 4] = v;
    }
    __syncthreads();

    const int tx = tid & 31;
    const int ty = tid >> 5;
    const int col = tx * 4;

    float acc[4][4];
#pragma unroll
    for (int r = 0; r < 4; ++r)
#pragma unroll
        for (int c = 0; c < 4; ++c) acc[r][c] = 0.f;

    for (int kb = 0; kb < K / 4; ++kb) {
        float4 w0 = *(const float4*)&W[(kb * 4 + 0) * 128 + col];
        float4 w1 = *(const float4*)&W[(kb * 4 + 1) * 128 + col];
        float4 w2 = *(const float4*)&W[(kb * 4 + 2) * 128 + col];
        float4 w3 = *(const float4*)&W[(kb * 4 + 3) * 128 + col];
        float4 xv[4];
#pragma unroll
        for (int r = 0; r < 4; ++r)
            xv[r] = *(const float4*)&xs[(ty * 4 + r) * LDX + kb * 4];
#pragma unroll
        for (int r = 0; r < 4; ++r) {
            acc[r][0] += xv[r].x * w0.x + xv[r].y * w1.x + xv[r].z * w2.x + xv[r].w * w3.x;
            acc[r][1] += xv[r].x * w0.y + xv[r].y * w1.y + xv[r].z * w2.y + xv[r].w * w3.y;
            acc[r][2] += xv[r].x * w0.z + xv[r].y * w1.z + xv[r].z * w2.z + xv[r].w * w3.z;
            acc[r][3] += xv[r].x * w0.w + xv[r].y * w1.w + xv[r].z * w2.w + xv[r].w * w3.w;
        }
    }

    float4 alv = *(const float4*)&al[col];
    float4 arv = *(const float4*)&ar[col];
    float elp[4], erp[4];
#pragma unroll
    for (int r = 0; r < 4; ++r) {
        int n = node0 + ty * 4 + r;
        float4 f = make_float4(acc[r][0], acc[r][1], acc[r][2], acc[r][3]);
        if (n < N) {
            __half2 p0 = __floats2half2_rn(f.x, f.y);
            __half2 p1 = __floats2half2_rn(f.z, f.w);
            union { __half2 h2[2]; uint2 u; } pk;
            pk.h2[0] = p0; pk.h2[1] = p1;
            *(uint2*)&feat[(size_t)n * 128 + col] = pk.u;
        }
        elp[r] = f.x * alv.x + f.y * alv.y + f.z * alv.z + f.w * alv.w;
        erp[r] = f.x * arv.x + f.y * arv.y + f.z * arv.z + f.w * arv.w;
    }
#pragma unroll
    for (int m = 1; m <= 8; m <<= 1) {
#pragma unroll
        for (int r = 0; r < 4; ++r) {
            elp[r] += __shfl_xor(elp[r], m, 64);
            erp[r] += __shfl_xor(erp[r], m, 64);
        }
    }
    int h = tx >> 4;
    if ((tx & 15) == 0) {
#pragma unroll
        for (int r = 0; r < 4; ++r) {
            int n = node0 + ty * 4 + r;
            if (n < N) {
                el[n * 2 + h] = elp[r];
                er[n * 2 + h] = erp[r];
            }
        }
    }
}

// ---------------------------------------------------------------------------
// Aggregation over fp16 feat rows (256 B each). One wave per node; 8-way
// edge split; lane ql owns 16 halves -> 2 dwordx4 loads, 8 rows (2KB)
// in flight per wave-iter. Merge via shfl_xor 8/16/32; head-mean via 4.
// ---------------------------------------------------------------------------

__global__ __launch_bounds__(256) void aggregate_kernel(
    const __half* __restrict__ feat, const float* __restrict__ el,
    const float* __restrict__ er, const int* __restrict__ deg,
    const int* __restrict__ ssrc, const float* __restrict__ bias,
    float* __restrict__ hout, int N) {
    const int wave = threadIdx.x >> 6;
    const int lane = threadIdx.x & 63;
    const int n = blockIdx.x * 4 + wave;
    if (n >= N) return;

    const int q = lane >> 3;
    const int ql = lane & 7;
    const int h = ql >> 2;
    const float er_h = er[n * 2 + h];
    const int start = n * SLOTS;
    int d = deg[n];
    if (d > SLOTS) d = SLOTS;

    float acc[16];
#pragma unroll
    for (int j = 0; j < 16; ++j) acc[j] = 0.f;
    float ssum = 0.f;

    for (int base = 0; base < d; base += 8) {
        int idx = base + q;
        bool valid = idx < d;
        int s = ssrc[start + (valid ? idx : 0)];
        float e = el[s * 2 + h] + er_h;
        e = e > 0.f ? e : 0.2f * e;
        float x = valid ? __expf(e) : 0.f;
        const float4* fp = (const float4*)(feat + (size_t)s * 128 + ql * 16);
        float4 ra = fp[0];
        float4 rb = fp[1];
        const __half2* ha = (const __half2*)&ra;
        const __half2* hb = (const __half2*)&rb;
        ssum += x;
#pragma unroll
        for (int j = 0; j < 4; ++j) {
            float2 fa = __half22float2(ha[j]);
            float2 fb = __half22float2(hb[j]);
            acc[j * 2 + 0] += x * fa.x;
            acc[j * 2 + 1] += x * fa.y;
            acc[8 + j * 2 + 0] += x * fb.x;
            acc[8 + j * 2 + 1] += x * fb.y;
        }
    }

#pragma unroll
    for (int m = 8; m <= 32; m <<= 1) {
#pragma unroll
        for (int j = 0; j < 16; ++j) acc[j] += __shfl_xor(acc[j], m, 64);
        ssum += __shfl_xor(ssum, m, 64);
    }

    float inv = (d > 0) ? 1.0f / ssum : 0.0f;
    float v[16];
#pragma unroll
    for (int j = 0; j < 4; ++j) {
        float4 b = *(const float4*)&bias[ql * 16 + j * 4];
        v[j * 4 + 0] = acc[j * 4 + 0] * inv + b.x;
        v[j * 4 + 1] = acc[j * 4 + 1] * inv + b.y;
        v[j * 4 + 2] = acc[j * 4 + 2] * inv + b.z;
        v[j * 4 + 3] = acc[j * 4 + 3] * inv + b.w;
    }

    float o[16];
#pragma unroll
    for (int j = 0; j < 16; ++j) {
        float p = __shfl_xor(v[j], 4, 64);
        float t = 0.5f * (v[j] + p);
        o[j] = t > 0.f ? t : expm1f(t);
    }
    if (lane < 4) {
#pragma unroll
        for (int j = 0; j < 4; ++j) {
            float4 w = make_float4(o[j * 4 + 0], o[j * 4 + 1], o[j * 4 + 2], o[j * 4 + 3]);
            *(float4*)&hout[(size_t)n * 64 + ql * 16 + j * 4] = w;
        }
    }
}

// ---------------------------------------------------------------------------

extern "C" void kernel_launch(void* const* d_in, const int* in_sizes, int n_in,
                              void* d_out, int out_size, void* d_ws, size_t ws_size,
                              hipStream_t stream) {
    const float* features = (const float*)d_in[0];
    const float* W1 = (const float*)d_in[1];
    const float* al1 = (const float*)d_in[2];
    const float* ar1 = (const float*)d_in[3];
    const float* b1 = (const float*)d_in[4];
    const float* W2 = (const float*)d_in[5];
    const float* al2 = (const float*)d_in[6];
    const float* ar2 = (const float*)d_in[7];
    const float* b2 = (const float*)d_in[8];
    const int* src = (const int*)d_in[9];
    const int* dst = (const int*)d_in[10];
    float* out = (float*)d_out;

    const int N = N_NODES;

    char* ws = (char*)d_ws;
    size_t off = 0;
    auto alloc = [&](size_t bytes) {
        void* p = ws + off;
        off = (off + bytes + 255) & ~255ULL;
        return p;
    };
    int* cursor   = (int*)alloc((size_t)N * 4);
    int* ssrc     = (int*)alloc((size_t)N * SLOTS * 4);   // 19.2 MB padded CSR
    __half* feath = (__half*)alloc((size_t)N * 128 * 2);  // 12.8 MB fp16 feat
    float* el     = (float*)alloc((size_t)N * 2 * 4);
    float* er     = (float*)alloc((size_t)N * 2 * 4);
    float* h1     = (float*)alloc((size_t)N * 64 * 4);

    // zero cursors (async memset is graph-capture safe; harness uses it too)
    hipMemsetAsync(cursor, 0, (size_t)N * 4, stream);

    // fused: CSR fill (blocks 0..831) || layer-1 GEMM (blocks 832..)
    fused_fill_gemm1<<<FILL_BLOCKS + GEMM1_BLOCKS, 256, 0, stream>>>(
        src, dst, cursor, ssrc, features, W1, al1, ar1, feath, el, er);

    aggregate_kernel<<<(N + 3) / 4, 256, 0, stream>>>(feath, el, er, cursor, ssrc,
                                                      b1, h1, N);
    // layer 2
    gemm_elr_kernel<64><<<(N + 31) / 32, 256, 0, stream>>>(h1, W2, al2, ar2,
                                                           feath, el, er, N);
    aggregate_kernel<<<(N + 3) / 4, 256, 0, stream>>>(feath, el, er, cursor, ssrc,
                                                      b2, out, N);
}